// Round 9
// baseline (298.964 us; speedup 1.0000x reference)
//
#include <hip/hip_runtime.h>
#include <math.h>

// e0 = 4*((1/3)^12 - (1/3)^6); 0.5*pe = 2*(c12 - c6) - 0.5*e0
static constexpr float HALF_NEG_E0 = 2.739720872e-3f; // -0.5*e0

#define T 256           // threads per block
#define B1 2500         // blocks for p3
#define SHIFT 10
#define BK 1024         // nodes per bucket (lid fits in 10 bits)
#define S 8             // sub-blocks per bucket in p4
#define FPSCALE 512.0f  // |f| <= 59.5 -> |int| <= 30450 < 32767
#define INV_FPSCALE (1.0f / 512.0f)

// ---- Phase 3 (fused): count -> reserve (global atomic per bucket) ->
//      compute -> LDS bucket-grouped staging -> coalesced flush --------------
// Requires NB <= 128, GPB*4 >= 128 (launcher guards).
__global__ __launch_bounds__(T)
void p3_fused(const float* __restrict__ bv, const int* __restrict__ dst,
              unsigned* __restrict__ gcur, int2* __restrict__ sorted,
              float* __restrict__ energy_ws, int E, int NB, int GPB, int cap)
{
    extern __shared__ int smem[];
    const int capb = GPB << 2;                    // max entries per block
    int2*          s_ent = (int2*)smem;           // [capb] packed (lo,hi)
    unsigned char* s_bkt = (unsigned char*)(smem + 2 * capb); // [capb]
    int* lcur = smem + 2 * capb + (capb + 3) / 4; // [NB] counts -> cursors
    int* gml  = lcur + NB;                        // [NB]

    const int r = blockIdx.x;
    const int t = threadIdx.x;

    for (int b = t; b < NB; b += T) lcur[b] = 0;
    __syncthreads();

    const int G  = (E + 3) >> 2;
    const int gs = r * GPB;
    const int ge = min(G, gs + GPB);
    const int4* __restrict__ d4 = (const int4*)dst;

    // ---- pass A: local bucket histogram (native LDS int atomics) -----------
    for (int g = gs + t; g < ge; g += T) {
        const int e0 = g << 2;
        if (e0 + 3 < E) {
            int4 d = d4[g];
            atomicAdd(&lcur[((unsigned)d.x) >> SHIFT], 1);
            atomicAdd(&lcur[((unsigned)d.y) >> SHIFT], 1);
            atomicAdd(&lcur[((unsigned)d.z) >> SHIFT], 1);
            atomicAdd(&lcur[((unsigned)d.w) >> SHIFT], 1);
        } else {
            for (int e = e0; e < E; ++e)
                atomicAdd(&lcur[((unsigned)dst[e]) >> SHIFT], 1);
        }
    }
    __syncthreads();

    // ---- 128-wide exclusive scan of local counts (NB <= 128) ---------------
    int* sc = (int*)s_ent;                        // reuse staging
    if (t < 128) sc[t] = (t < NB) ? lcur[t] : 0;
    __syncthreads();
#pragma unroll
    for (int off = 1; off < 128; off <<= 1) {
        int a0 = (t < 128 && t >= off) ? sc[t - off] : 0;
        __syncthreads();
        if (t < 128) sc[t] += a0;
        __syncthreads();
    }
    // ---- reserve space in each bucket's region (one global atomic each) ----
    if (t < NB) {
        int cnt = lcur[t];
        int ex  = sc[t] - cnt;                    // exclusive prefix
        unsigned ret = atomicAdd(&gcur[t], (unsigned)cnt);
        gml[t]  = t * cap + (int)ret - ex;
        lcur[t] = ex;                             // becomes slot cursor
    }
    __syncthreads();

    // ---- pass B: compute forces + energy, stage bucket-grouped -------------
    const float4* __restrict__ bv4 = (const float4*)bv;
    float esum = 0.0f;

    for (int g = gs + t; g < ge; g += T) {
        const int e0 = g << 2;
        float ex4[4], ey[4], ez[4]; int dd[4];
        int nk;
        if (e0 + 3 < E) {
            float4 a  = bv4[3 * g + 0];
            float4 b2 = bv4[3 * g + 1];
            float4 c  = bv4[3 * g + 2];
            int4 d = d4[g];
            ex4[0] = a.x;  ey[0] = a.y;  ez[0] = a.z;
            ex4[1] = a.w;  ey[1] = b2.x; ez[1] = b2.y;
            ex4[2] = b2.z; ey[2] = b2.w; ez[2] = c.x;
            ex4[3] = c.y;  ey[3] = c.z;  ez[3] = c.w;
            dd[0] = d.x; dd[1] = d.y; dd[2] = d.z; dd[3] = d.w;
            nk = 4;
        } else {
            nk = E - e0;
            for (int k = 0; k < nk; ++k) {
                ex4[k] = bv[3 * (e0 + k) + 0];
                ey[k]  = bv[3 * (e0 + k) + 1];
                ez[k]  = bv[3 * (e0 + k) + 2];
                dd[k]  = dst[e0 + k];
            }
        }
        for (int k = 0; k < nk; ++k) {
            float x = ex4[k], y = ey[k], z = ez[k];
            float r2  = x * x + y * y + z * z;
            float inv = 1.0f / r2;
            float c6  = inv * inv * inv;
            float c12 = c6 * c6;
            esum += 2.0f * (c12 - c6) + HALF_NEG_E0;
            float fs = -24.0f * (2.0f * c12 - c6) * inv * FPSCALE;
            int ix = __float2int_rn(fs * x);
            int iy = __float2int_rn(fs * y);
            int iz = __float2int_rn(fs * z);
            int b  = ((unsigned)dd[k]) >> SHIFT;
            int slot = atomicAdd(&lcur[b], 1);    // native LDS int atomic
            s_ent[slot] = make_int2((ix & 0xffff) | (iy << 16),
                                    (iz & 0xffff) | ((dd[k] & (BK - 1)) << 16));
            s_bkt[slot] = (unsigned char)b;
        }
    }
    __syncthreads();

    // ---- flush: bucket order -> ~208 B contiguous runs ---------------------
    const int nloc = max(0, min(E, ge << 2) - (gs << 2));
    for (int i = t; i < nloc; i += T) {
        int2 e = s_ent[i];
        sorted[gml[(int)s_bkt[i]] + i] = e;
    }

    // ---- energy: wave shuffle -> LDS -> one global atomic per block --------
#pragma unroll
    for (int off = 32; off > 0; off >>= 1)
        esum += __shfl_down(esum, off, 64);
    __shared__ float wsum[T / 64];
    const int wid = t >> 6, lid = t & 63;
    if (lid == 0) wsum[wid] = esum;
    __syncthreads();
    if (t == 0) {
        float s = 0.0f;
        for (int w = 0; w < T / 64; ++w) s += wsum[w];
        unsafeAtomicAdd(energy_ws, s);
    }
}

// ------- Phase 4 (fused): partial reduce + last-block merge -----------------
__global__ __launch_bounds__(T)
void p4_fused(const int2* __restrict__ sorted, const unsigned* __restrict__ gcur,
              int* __restrict__ partial, unsigned* __restrict__ done,
              const float* __restrict__ energy_ws, float* __restrict__ out,
              float* __restrict__ forces, float* __restrict__ analytic,
              int N, int cap)
{
    __shared__ int acc[BK * 3];                   // 12 KB
    const int b = blockIdx.x >> 3;                // / S
    const int q = blockIdx.x & (S - 1);           // % S
    for (int t = threadIdx.x; t < BK * 3; t += T) acc[t] = 0;
    __syncthreads();
    const unsigned len = gcur[b];
    const unsigned s0  = (unsigned)b * (unsigned)cap;   // cap even -> 16B align
    unsigned chunk = (((len + S - 1) / S) + 1) & ~1u;   // even chunks
    const unsigned c0 = min(len, q * chunk);
    const unsigned c1 = min(len, c0 + chunk);
    for (unsigned i = c0 + 2 * threadIdx.x; i < c1; i += 2 * T) {
        if (i + 1 < c1) {
            int4 v = *(const int4*)(sorted + s0 + i);   // two entries
            int lid0 = ((unsigned)v.y) >> 16;
            atomicAdd(&acc[lid0 * 3 + 0], (int)(short)(v.x & 0xffff));
            atomicAdd(&acc[lid0 * 3 + 1], v.x >> 16);
            atomicAdd(&acc[lid0 * 3 + 2], (int)(short)(v.y & 0xffff));
            int lid1 = ((unsigned)v.w) >> 16;
            atomicAdd(&acc[lid1 * 3 + 0], (int)(short)(v.z & 0xffff));
            atomicAdd(&acc[lid1 * 3 + 1], v.z >> 16);
            atomicAdd(&acc[lid1 * 3 + 2], (int)(short)(v.w & 0xffff));
        } else {
            int2 v = sorted[s0 + i];
            int lid0 = ((unsigned)v.y) >> 16;
            atomicAdd(&acc[lid0 * 3 + 0], (int)(short)(v.x & 0xffff));
            atomicAdd(&acc[lid0 * 3 + 1], v.x >> 16);
            atomicAdd(&acc[lid0 * 3 + 2], (int)(short)(v.y & 0xffff));
        }
    }
    __syncthreads();
    int* P = partial + ((size_t)b * S + q) * (BK * 3);
    for (int t = threadIdx.x; t < BK * 3; t += T) P[t] = acc[t];

    // ---- last block of this bucket merges ----------------------------------
    __threadfence();                              // make partial visible (device)
    __shared__ unsigned old;
    if (threadIdx.x == 0) old = atomicAdd(&done[b], 1u);
    __syncthreads();
    if (old != S - 1) return;
    __threadfence();                              // acquire partials

    const int node0 = b * BK;
    const int nl3   = (min(N, node0 + BK) - node0) * 3;
    const int* Pb   = partial + (size_t)b * S * (BK * 3);
    float* A = analytic + (size_t)node0 * 3;
    float* F = forces   + (size_t)node0 * 3;
    for (int t = threadIdx.x; t < nl3; t += T) {
        int s = 0;
#pragma unroll
        for (int q2 = 0; q2 < S; ++q2)
            s += Pb[q2 * (BK * 3) + t];
        float v = (float)s * INV_FPSCALE;
        A[t] = v;
        F[t] = -0.5f * v;
    }
    if (b == 0 && threadIdx.x == 0) out[0] = *energy_ws;  // p3 done (stream order)
}

// ---------------- Fallback (R1 kernel) if workspace too small ---------------
__global__ __launch_bounds__(T)
void lj_fallback(const float* __restrict__ bv, const int* __restrict__ dst,
                 float* __restrict__ out_energy, float* __restrict__ analytic, int E)
{
    const int e = blockIdx.x * blockDim.x + threadIdx.x;
    float esum = 0.0f;
    if (e < E) {
        float x = bv[3 * e], y = bv[3 * e + 1], z = bv[3 * e + 2];
        float r2 = x * x + y * y + z * z;
        float inv = 1.0f / r2;
        float c6 = inv * inv * inv, c12 = c6 * c6;
        esum = 2.0f * (c12 - c6) + HALF_NEG_E0;
        float fs = -24.0f * (2.0f * c12 - c6) * inv;
        float* p = analytic + 3 * (size_t)dst[e];
        unsafeAtomicAdd(p + 0, fs * x);
        unsafeAtomicAdd(p + 1, fs * y);
        unsafeAtomicAdd(p + 2, fs * z);
    }
#pragma unroll
    for (int off = 32; off > 0; off >>= 1) esum += __shfl_down(esum, off, 64);
    __shared__ float wsum[T / 64];
    if ((threadIdx.x & 63) == 0) wsum[threadIdx.x >> 6] = esum;
    __syncthreads();
    if (threadIdx.x == 0) {
        float s = 0.0f;
        for (int w = 0; w < T / 64; ++w) s += wsum[w];
        unsafeAtomicAdd(out_energy, s);
    }
}

__global__ __launch_bounds__(T)
void lj_scale(const float* __restrict__ analytic, float* __restrict__ forces, int n)
{
    int i = blockIdx.x * blockDim.x + threadIdx.x;
    if (i < n) forces[i] = -0.5f * analytic[i];
}

extern "C" void kernel_launch(void* const* d_in, const int* in_sizes, int n_in,
                              void* d_out, int out_size, void* d_ws, size_t ws_size,
                              hipStream_t stream)
{
    const float* bv  = (const float*)d_in[0];
    const int*   dst = (const int*)d_in[1];
    const int E = in_sizes[0] / 3;
    const int N = (out_size - 1) / 6;   // out = [energy | forces(3N) | analytic(3N)]

    float* out      = (float*)d_out;
    float* energy   = out;
    float* forces   = out + 1;
    float* analytic = out + 1 + (size_t)3 * N;

    const int NB  = (N + BK - 1) / BK;
    const int G   = (E + 3) / 4;
    const int GPB = (G + B1 - 1) / B1;

    // per-bucket region capacity: mean + 10 sigma + 64, rounded even
    const int avg = E / NB;
    int cap = avg + 10 * (int)ceil(sqrt((double)avg)) + 64;
    cap = (cap + 1) & ~1;

    auto al = [](size_t x) { return (x + 255) & ~(size_t)255; };
    const size_t sorted_bytes  = al((size_t)NB * cap * 8);
    // control block: gcur[NB] | done[NB] | energy_ws[1]  (single memset)
    const size_t ctrl_bytes    = al(((size_t)2 * NB + 1) * 4);
    const size_t partial_bytes = al((size_t)NB * S * (BK * 3) * 4);
    const size_t need = sorted_bytes + ctrl_bytes + partial_bytes;

    const int capb = GPB * 4;
    // staging int2[capb] + uchar[capb] (rounded to ints) + 2*NB ints
    const size_t smem_bytes = (size_t)capb * 8 + ((size_t)(capb + 3) / 4) * 4
                            + (size_t)2 * NB * 4;

    if (NB <= 128 && capb >= 128 && smem_bytes <= 64000 && ws_size >= need) {
        char* w = (char*)d_ws;
        int2*     sorted    = (int2*)w;      w += sorted_bytes;
        unsigned* gcur      = (unsigned*)w;
        unsigned* done      = gcur + NB;
        float*    energy_ws = (float*)(gcur + 2 * NB);
        w += ctrl_bytes;
        int*      partial   = (int*)w;

        hipMemsetAsync(gcur, 0, ((size_t)2 * NB + 1) * 4, stream);
        p3_fused<<<B1, T, smem_bytes, stream>>>(bv, dst, gcur, sorted, energy_ws,
                                                E, NB, GPB, cap);
        p4_fused<<<NB * S, T, 0, stream>>>(sorted, gcur, partial, done, energy_ws,
                                           out, forces, analytic, N, cap);
    } else {
        hipMemsetAsync(d_out, 0, (size_t)out_size * sizeof(float), stream);
        lj_fallback<<<(E + T - 1) / T, T, 0, stream>>>(bv, dst, energy, analytic, E);
        const int n3 = 3 * N;
        lj_scale<<<(n3 + T - 1) / T, T, 0, stream>>>(analytic, forces, n3);
    }
}

// Round 10
// 270.627 us; speedup vs baseline: 1.1047x; 1.1047x over previous
//
#include <hip/hip_runtime.h>
#include <math.h>

// e0 = 4*((1/3)^12 - (1/3)^6); 0.5*pe = 2*(c12 - c6) - 0.5*e0
static constexpr float HALF_NEG_E0 = 2.739720872e-3f; // -0.5*e0

#define T 256           // threads per block
#define B1 5000         // blocks for p3 (small staging -> 8 blocks/CU resident)
#define SHIFT 10
#define BK 1024         // nodes per bucket (lid fits in 10 bits)
#define S 16            // sub-blocks per bucket in p4a
#define FPSCALE 512.0f  // |f| <= 59.5 -> |int| <= 30450 < 32767
#define INV_FPSCALE (1.0f / 512.0f)

// ---- Phase 3 (fused): count -> reserve (global atomic per bucket) ->
//      compute -> LDS bucket-grouped staging -> coalesced flush --------------
// Requires NB <= 128, GPB*4 >= 128 (launcher guards).
__global__ __launch_bounds__(T)
void p3_fused(const float* __restrict__ bv, const int* __restrict__ dst,
              unsigned* __restrict__ gcur, int2* __restrict__ sorted,
              float* __restrict__ energy_ws, int E, int NB, int GPB, int cap)
{
    extern __shared__ int smem[];
    const int capb = GPB << 2;                    // max entries per block
    int2*          s_ent = (int2*)smem;           // [capb] packed (lo,hi)
    unsigned char* s_bkt = (unsigned char*)(smem + 2 * capb); // [capb]
    int* lcur = smem + 2 * capb + (capb + 3) / 4; // [NB] counts -> cursors
    int* gml  = lcur + NB;                        // [NB]

    const int r = blockIdx.x;
    const int t = threadIdx.x;

    for (int b = t; b < NB; b += T) lcur[b] = 0;
    __syncthreads();

    const int G  = (E + 3) >> 2;
    const int gs = r * GPB;
    const int ge = min(G, gs + GPB);
    const int4* __restrict__ d4 = (const int4*)dst;

    // ---- pass A: local bucket histogram (native LDS int atomics) -----------
    for (int g = gs + t; g < ge; g += T) {
        const int e0 = g << 2;
        if (e0 + 3 < E) {
            int4 d = d4[g];
            atomicAdd(&lcur[((unsigned)d.x) >> SHIFT], 1);
            atomicAdd(&lcur[((unsigned)d.y) >> SHIFT], 1);
            atomicAdd(&lcur[((unsigned)d.z) >> SHIFT], 1);
            atomicAdd(&lcur[((unsigned)d.w) >> SHIFT], 1);
        } else {
            for (int e = e0; e < E; ++e)
                atomicAdd(&lcur[((unsigned)dst[e]) >> SHIFT], 1);
        }
    }
    __syncthreads();

    // ---- 128-wide exclusive scan of local counts (NB <= 128) ---------------
    int* sc = (int*)s_ent;                        // reuse staging
    if (t < 128) sc[t] = (t < NB) ? lcur[t] : 0;
    __syncthreads();
#pragma unroll
    for (int off = 1; off < 128; off <<= 1) {
        int a0 = (t < 128 && t >= off) ? sc[t - off] : 0;
        __syncthreads();
        if (t < 128) sc[t] += a0;
        __syncthreads();
    }
    // ---- reserve space in each bucket's region (one global atomic each) ----
    if (t < NB) {
        int cnt = lcur[t];
        int ex  = sc[t] - cnt;                    // exclusive prefix
        unsigned ret = atomicAdd(&gcur[t], (unsigned)cnt);
        gml[t]  = t * cap + (int)ret - ex;
        lcur[t] = ex;                             // becomes slot cursor
    }
    __syncthreads();

    // ---- pass B: compute forces + energy, stage bucket-grouped -------------
    const float4* __restrict__ bv4 = (const float4*)bv;
    float esum = 0.0f;

    for (int g = gs + t; g < ge; g += T) {
        const int e0 = g << 2;
        float ex4[4], ey[4], ez[4]; int dd[4];
        int nk;
        if (e0 + 3 < E) {
            float4 a  = bv4[3 * g + 0];
            float4 b2 = bv4[3 * g + 1];
            float4 c  = bv4[3 * g + 2];
            int4 d = d4[g];
            ex4[0] = a.x;  ey[0] = a.y;  ez[0] = a.z;
            ex4[1] = a.w;  ey[1] = b2.x; ez[1] = b2.y;
            ex4[2] = b2.z; ey[2] = b2.w; ez[2] = c.x;
            ex4[3] = c.y;  ey[3] = c.z;  ez[3] = c.w;
            dd[0] = d.x; dd[1] = d.y; dd[2] = d.z; dd[3] = d.w;
            nk = 4;
        } else {
            nk = E - e0;
            for (int k = 0; k < nk; ++k) {
                ex4[k] = bv[3 * (e0 + k) + 0];
                ey[k]  = bv[3 * (e0 + k) + 1];
                ez[k]  = bv[3 * (e0 + k) + 2];
                dd[k]  = dst[e0 + k];
            }
        }
        for (int k = 0; k < nk; ++k) {
            float x = ex4[k], y = ey[k], z = ez[k];
            float r2  = x * x + y * y + z * z;
            float inv = 1.0f / r2;
            float c6  = inv * inv * inv;
            float c12 = c6 * c6;
            esum += 2.0f * (c12 - c6) + HALF_NEG_E0;
            float fs = -24.0f * (2.0f * c12 - c6) * inv * FPSCALE;
            int ix = __float2int_rn(fs * x);
            int iy = __float2int_rn(fs * y);
            int iz = __float2int_rn(fs * z);
            int b  = ((unsigned)dd[k]) >> SHIFT;
            int slot = atomicAdd(&lcur[b], 1);    // native LDS int atomic
            s_ent[slot] = make_int2((ix & 0xffff) | (iy << 16),
                                    (iz & 0xffff) | ((dd[k] & (BK - 1)) << 16));
            s_bkt[slot] = (unsigned char)b;
        }
    }
    __syncthreads();

    // ---- flush: bucket order -> ~104 B contiguous runs ---------------------
    const int nloc = max(0, min(E, ge << 2) - (gs << 2));
    for (int i = t; i < nloc; i += T) {
        int2 e = s_ent[i];
        sorted[gml[(int)s_bkt[i]] + i] = e;
    }

    // ---- energy: wave shuffle -> LDS -> one global atomic per block --------
#pragma unroll
    for (int off = 32; off > 0; off >>= 1)
        esum += __shfl_down(esum, off, 64);
    __shared__ float wsum[T / 64];
    const int wid = t >> 6, lid = t & 63;
    if (lid == 0) wsum[wid] = esum;
    __syncthreads();
    if (t == 0) {
        float s = 0.0f;
        for (int w = 0; w < T / 64; ++w) s += wsum[w];
        unsafeAtomicAdd(energy_ws, s);
    }
}

// ------- Phase 4a: per-(bucket, sub-chunk) partial reduce (int LDS atomics) -
__global__ __launch_bounds__(T)
void p4a_partial(const int2* __restrict__ sorted, const unsigned* __restrict__ gcur,
                 int* __restrict__ partial, int cap)
{
    __shared__ int acc[BK * 3];                   // 12 KB
    const int b = blockIdx.x >> 4;                // / S
    const int q = blockIdx.x & (S - 1);           // % S
    for (int t = threadIdx.x; t < BK * 3; t += T) acc[t] = 0;
    __syncthreads();
    const unsigned len = gcur[b];
    const unsigned s0  = (unsigned)b * (unsigned)cap;   // cap even -> 16B align
    unsigned chunk = (((len + S - 1) / S) + 1) & ~1u;   // even chunks
    const unsigned c0 = min(len, q * chunk);
    const unsigned c1 = min(len, c0 + chunk);
    for (unsigned i = c0 + 2 * threadIdx.x; i < c1; i += 2 * T) {
        if (i + 1 < c1) {
            int4 v = *(const int4*)(sorted + s0 + i);   // two entries
            int lid0 = ((unsigned)v.y) >> 16;
            atomicAdd(&acc[lid0 * 3 + 0], (int)(short)(v.x & 0xffff));
            atomicAdd(&acc[lid0 * 3 + 1], v.x >> 16);
            atomicAdd(&acc[lid0 * 3 + 2], (int)(short)(v.y & 0xffff));
            int lid1 = ((unsigned)v.w) >> 16;
            atomicAdd(&acc[lid1 * 3 + 0], (int)(short)(v.z & 0xffff));
            atomicAdd(&acc[lid1 * 3 + 1], v.z >> 16);
            atomicAdd(&acc[lid1 * 3 + 2], (int)(short)(v.w & 0xffff));
        } else {
            int2 v = sorted[s0 + i];
            int lid0 = ((unsigned)v.y) >> 16;
            atomicAdd(&acc[lid0 * 3 + 0], (int)(short)(v.x & 0xffff));
            atomicAdd(&acc[lid0 * 3 + 1], v.x >> 16);
            atomicAdd(&acc[lid0 * 3 + 2], (int)(short)(v.y & 0xffff));
        }
    }
    __syncthreads();
    int* P = partial + ((size_t)b * S + q) * (BK * 3);
    for (int t = threadIdx.x; t < BK * 3; t += T) P[t] = acc[t];
}

// ------- Phase 4b: merge S int partials per bucket, write both outputs ------
__global__ __launch_bounds__(T)
void p4b_merge(const int* __restrict__ partial, const float* __restrict__ energy_ws,
               float* __restrict__ out, float* __restrict__ forces,
               float* __restrict__ analytic, int N)
{
    if (blockIdx.x == 0 && threadIdx.x == 0)
        out[0] = *energy_ws;                      // p3 done by stream order
    const int i = blockIdx.x * T + threadIdx.x;   // output component idx in [0, 3N)
    if (i >= 3 * N) return;
    const int node = i / 3;
    const int b = node >> SHIFT;
    const int lidc = i - b * (BK * 3);
    int s = 0;
#pragma unroll
    for (int q = 0; q < S; ++q)
        s += partial[((size_t)b * S + q) * (BK * 3) + lidc];
    float v = (float)s * INV_FPSCALE;
    analytic[i] = v;
    forces[i] = -0.5f * v;
}

// ---------------- Fallback (R1 kernel) if workspace too small ---------------
__global__ __launch_bounds__(T)
void lj_fallback(const float* __restrict__ bv, const int* __restrict__ dst,
                 float* __restrict__ out_energy, float* __restrict__ analytic, int E)
{
    const int e = blockIdx.x * blockDim.x + threadIdx.x;
    float esum = 0.0f;
    if (e < E) {
        float x = bv[3 * e], y = bv[3 * e + 1], z = bv[3 * e + 2];
        float r2 = x * x + y * y + z * z;
        float inv = 1.0f / r2;
        float c6 = inv * inv * inv, c12 = c6 * c6;
        esum = 2.0f * (c12 - c6) + HALF_NEG_E0;
        float fs = -24.0f * (2.0f * c12 - c6) * inv;
        float* p = analytic + 3 * (size_t)dst[e];
        unsafeAtomicAdd(p + 0, fs * x);
        unsafeAtomicAdd(p + 1, fs * y);
        unsafeAtomicAdd(p + 2, fs * z);
    }
#pragma unroll
    for (int off = 32; off > 0; off >>= 1) esum += __shfl_down(esum, off, 64);
    __shared__ float wsum[T / 64];
    if ((threadIdx.x & 63) == 0) wsum[threadIdx.x >> 6] = esum;
    __syncthreads();
    if (threadIdx.x == 0) {
        float s = 0.0f;
        for (int w = 0; w < T / 64; ++w) s += wsum[w];
        unsafeAtomicAdd(out_energy, s);
    }
}

__global__ __launch_bounds__(T)
void lj_scale(const float* __restrict__ analytic, float* __restrict__ forces, int n)
{
    int i = blockIdx.x * blockDim.x + threadIdx.x;
    if (i < n) forces[i] = -0.5f * analytic[i];
}

extern "C" void kernel_launch(void* const* d_in, const int* in_sizes, int n_in,
                              void* d_out, int out_size, void* d_ws, size_t ws_size,
                              hipStream_t stream)
{
    const float* bv  = (const float*)d_in[0];
    const int*   dst = (const int*)d_in[1];
    const int E = in_sizes[0] / 3;
    const int N = (out_size - 1) / 6;   // out = [energy | forces(3N) | analytic(3N)]

    float* out      = (float*)d_out;
    float* energy   = out;
    float* forces   = out + 1;
    float* analytic = out + 1 + (size_t)3 * N;

    const int NB  = (N + BK - 1) / BK;
    const int G   = (E + 3) / 4;
    const int GPB = (G + B1 - 1) / B1;

    // per-bucket region capacity: mean + 10 sigma + 64, rounded even
    const int avg = E / NB;
    int cap = avg + 10 * (int)ceil(sqrt((double)avg)) + 64;
    cap = (cap + 1) & ~1;

    auto al = [](size_t x) { return (x + 255) & ~(size_t)255; };
    const size_t sorted_bytes  = al((size_t)NB * cap * 8);
    // control block: gcur[NB] | energy_ws[1]  (single memset)
    const size_t ctrl_bytes    = al(((size_t)NB + 1) * 4);
    const size_t partial_bytes = al((size_t)NB * S * (BK * 3) * 4);
    const size_t need = sorted_bytes + ctrl_bytes + partial_bytes;

    const int capb = GPB * 4;
    // staging int2[capb] + uchar[capb] (rounded to ints) + 2*NB ints
    const size_t smem_bytes = (size_t)capb * 8 + ((size_t)(capb + 3) / 4) * 4
                            + (size_t)2 * NB * 4;

    if (NB <= 128 && capb >= 128 && smem_bytes <= 64000 && ws_size >= need) {
        char* w = (char*)d_ws;
        int2*     sorted    = (int2*)w;      w += sorted_bytes;
        unsigned* gcur      = (unsigned*)w;
        float*    energy_ws = (float*)(gcur + NB);
        w += ctrl_bytes;
        int*      partial   = (int*)w;

        hipMemsetAsync(gcur, 0, ((size_t)NB + 1) * 4, stream);
        p3_fused   <<<B1, T, smem_bytes, stream>>>(bv, dst, gcur, sorted, energy_ws,
                                                   E, NB, GPB, cap);
        p4a_partial<<<NB * S, T, 0, stream>>>(sorted, gcur, partial, cap);
        p4b_merge  <<<(3 * N + T - 1) / T, T, 0, stream>>>(partial, energy_ws, out,
                                                           forces, analytic, N);
    } else {
        hipMemsetAsync(d_out, 0, (size_t)out_size * sizeof(float), stream);
        lj_fallback<<<(E + T - 1) / T, T, 0, stream>>>(bv, dst, energy, analytic, E);
        const int n3 = 3 * N;
        lj_scale<<<(n3 + T - 1) / T, T, 0, stream>>>(analytic, forces, n3);
    }
}